// Round 8
// baseline (414.007 us; speedup 1.0000x reference)
//
#include <hip/hip_runtime.h>
#include <hip/hip_bf16.h>

// Problem constants (fixed by reference)
#define Nn 16000
#define Ee 256000
#define Tt 5
#define GATES 512  // 4*LH
#define NREP 8     // one replica per XCD (XCC_ID-indexed)
#define CAP 16     // slots per (node, XCD-replica); in-degree ~Poisson(2), P(>16)~1e-11

// NOTE (R2): no cooperative-kernel fusion (grid.sync across XCDs = 397 µs stall).
// NOTE (R4): slot layout [i][r][n] (dense in n); [r][n][16] fetched 8 MB at 2.5/16 util.
// NOTE (R6): inline source-dinv loses to the dinv_xs precompute dispatch.
// NOTE (R7): in-recur fold loses (~+13 µs) to standalone gcn_agg (R5: recur 95.3).
// NOTE (R1..R7): residual ~90 µs is invariant to dispatch count (89-102 across 3-5
// dispatches) -> harness-fixed restore cost. Only lever left: recur_all itself.
// R8: convoy fix — 256-thr/16-node blocks (4-wave barrier groups), 4 blocks/CU,
// each wave covers unit-groups {uq, uq+4} via pair-interleaved weight swizzle.

typedef _Float16 f16;
typedef __attribute__((ext_vector_type(8))) _Float16 f16x8;
typedef __attribute__((ext_vector_type(4))) float f32x4;

// ---- workspace layout (float units) ----
#define OFF_DINV 0
#define OFF_XS   (OFF_DINV + Nn)               // Nn*8 fp32: xs rows (32B)
#define OFF_AGG  (OFF_XS + Nn*8)               // Nn*8 fp32: folded agg rows
#define OFF_CNT  (OFF_AGG + Nn*8)              // NREP*Nn ints
#define OFF_SLOT (OFF_CNT + NREP*Nn)           // NREP*Nn*CAP ints, [i][r][n]
#define OFF_B0   (OFF_SLOT + NREP*Nn*CAP)      // 512
#define OFF_B1   (OFF_B0 + GATES)              // 512
#define OFF_W0S  (OFF_B1 + GATES)              // 512*192 f16 (pair-interleaved swizzle)
#define OFF_W1S  (OFF_W0S + 512*192/2)         // 512*256 f16 (pair-interleaved swizzle)
#define OFF_PWS  (OFF_W1S + 512*256/2)         // 64*128 f16
#define OFF_END  (OFF_PWS + 64*128/2)

__device__ __forceinline__ float fsig(float x) { return 1.f / (1.f + __expf(-x)); }
__device__ __forceinline__ float ftanh(float x) { return 1.f - 2.f / (1.f + __expf(2.f * x)); }

__device__ __forceinline__ unsigned xcc_id() {
    unsigned x;
    asm volatile("s_getreg_b32 %0, hwreg(HW_REG_XCC_ID)" : "=s"(x));
    return x & (NREP - 1);
}

// ---- prep + fill ----
// Pair-interleaved B-frag swizzle for 4-wave recur blocks: wave q handles unit
// groups g=q (pair 0) and g=q+4 (pair 1). Element (qrow=gate*128+g*16+l, k):
//   addr = ((((gq*NKT + kt)*4 + gate)*2 + pair)*64 + quad*16 + l)*8 + j
// with gq=g&3, pair=g>>2, kt=k>>5, quad=(k>>3)&3, j=k&7. Both pairs of a
// (wave,kt,gate) are adjacent 512-f16 blocks -> one base, +512 offset.
__global__ void prep_fill(const float* __restrict__ w_ih0, const float* __restrict__ w_hh0,
                          const float* __restrict__ b_ih0, const float* __restrict__ b_hh0,
                          const float* __restrict__ w_ih1, const float* __restrict__ w_hh1,
                          const float* __restrict__ b_ih1, const float* __restrict__ b_hh1,
                          const float* __restrict__ pw1, const int* __restrict__ ei,
                          f16* __restrict__ W0S, f16* __restrict__ W1S, f16* __restrict__ pwS,
                          float* __restrict__ B0, float* __restrict__ B1,
                          int* __restrict__ cnt, int* __restrict__ slot) {
    int b = blockIdx.x, t = threadIdx.x;
    if (b >= 1092) {
        int e = (b - 1092) * 256 + t;          // 1000 blocks * 256 = Ee exactly
        int s = ei[e], d = ei[Ee + e];
        unsigned r = xcc_id();
        int pos = __hip_atomic_fetch_add(&cnt[r * Nn + d], 1,
                                         __ATOMIC_RELAXED, __HIP_MEMORY_SCOPE_WORKGROUP);
        if (pos < CAP)
            slot[((size_t)pos * NREP + r) * Nn + d] = s;
        return;
    }
    if (b < 512) {
        if (t < 192) {
            int q = b, k = t;
            float v = (k < 64) ? w_ih0[q * 64 + k] : w_hh0[q * 128 + (k - 64)];
            int g = (q & 127) >> 4, l = q & 15, gate = q >> 7;
            int kt = k >> 5, quad = (k >> 3) & 3, j = k & 7;
            int gq = g & 3, pair = g >> 2;
            W0S[((((gq * 6 + kt) * 4 + gate) * 2 + pair) * 64 + quad * 16 + l) * 8 + j] = (f16)v;
        }
    } else if (b < 1024) {
        int q = b - 512, k = t;
        float v = (k < 128) ? w_ih1[q * 128 + k] : w_hh1[q * 128 + (k - 128)];
        int g = (q & 127) >> 4, l = q & 15, gate = q >> 7;
        int kt = k >> 5, quad = (k >> 3) & 3, j = k & 7;
        int gq = g & 3, pair = g >> 2;
        W1S[((((gq * 8 + kt) * 4 + gate) * 2 + pair) * 64 + quad * 16 + l) * 8 + j] = (f16)v;
    } else if (b < 1028) {
        int idx = (b - 1024) * 256 + t;
        if (idx < 512) B0[idx] = b_ih0[idx] + b_hh0[idx];
        else           B1[idx - 512] = b_ih1[idx - 512] + b_hh1[idx - 512];
    } else {
        if (t < 128) {
            int u = b - 1028, k = t;
            int g = u >> 4, lp = u & 15;
            int kt = k >> 5, quad = (k >> 3) & 3, j = k & 7;
            pwS[((g * 4 + kt) * 64 + quad * 16 + lp) * 8 + j] = (f16)pw1[u * 128 + k];
        }
    }
}

// ---- dinv + prescale (R5-verified) ----
__global__ void dinv_xs(const int* __restrict__ cnt, const float* __restrict__ x,
                        float* __restrict__ dinv, float* __restrict__ xs) {
    int n = blockIdx.x * blockDim.x + threadIdx.x;
    if (n >= Nn) return;
    int deg = 1;  // self loop
    #pragma unroll
    for (int r = 0; r < NREP; ++r) deg += cnt[r * Nn + n];
    float dv = rsqrtf((float)deg);
    dinv[n] = dv;
    #pragma unroll
    for (int t = 0; t < Tt; ++t) xs[n * 8 + t] = x[n * Tt + t] * dv;
}

// ---- gather-aggregate (R5-verified: recur 95.3 with this feeding it) ----
__global__ void gcn_agg(const int* __restrict__ cnt, const int* __restrict__ slot,
                        const float* __restrict__ dinv, const float* __restrict__ xs,
                        float* __restrict__ agg) {
    const int tid = threadIdx.x;
    const int nl = tid >> 3;          // 0..31
    const int r = tid & 7;
    const int n = blockIdx.x * 32 + nl;
    int c = cnt[r * Nn + n];
    c = min(c, CAP);
    float s0 = 0.f, s1 = 0.f, s2 = 0.f, s3 = 0.f, s4 = 0.f;
    for (int i = 0; i < c; ++i) {
        int src = slot[((size_t)i * NREP + r) * Nn + n];
        const float* xr = xs + (size_t)src * 8;
        float4 v4 = *(const float4*)xr;
        s0 += v4.x; s1 += v4.y; s2 += v4.z; s3 += v4.w; s4 += xr[4];
    }
    #pragma unroll
    for (int m = 1; m < 8; m <<= 1) {
        s0 += __shfl_xor(s0, m);
        s1 += __shfl_xor(s1, m);
        s2 += __shfl_xor(s2, m);
        s3 += __shfl_xor(s3, m);
        s4 += __shfl_xor(s4, m);
    }
    if (r == 0) {
        float dv = dinv[n];
        const float* xn = xs + (size_t)n * 8;
        float* ap = agg + (size_t)n * 8;
        ap[0] = (s0 + xn[0]) * dv;
        ap[1] = (s1 + xn[1]) * dv;
        ap[2] = (s2 + xn[2]) * dv;
        ap[3] = (s3 + xn[3]) * dv;
        ap[4] = (s4 + xn[4]) * dv;
    }
}

// ---- fused recurrence v8: 4-wave/16-node blocks, 4 blocks/CU ----
// Convoy fix: barriers sync 4 waves (was 8); 4 independent blocks per CU overlap
// each other's barrier/memory stalls. Each wave computes unit-groups {uq, uq+4}
// (pair-interleaved W swizzle: one base, pair at +512 f16). A-frags (node rows)
// are shared across the pair -> LDS reads and feat repack halve per wave.
// LDS 16.4 KB/block; VGPR capped 128 by __launch_bounds__(256,4).
__global__ __launch_bounds__(256, 4) void recur_all(
    const float* __restrict__ agg,
    const float* __restrict__ gw, const float* __restrict__ gb,
    const f16* __restrict__ W0S, const f16* __restrict__ W1S,
    const float* __restrict__ B0, const float* __restrict__ B1,
    const f16* __restrict__ pwS, const float* __restrict__ pb1,
    const float* __restrict__ pw2, const float* __restrict__ pb2,
    const float* __restrict__ x, float* __restrict__ out) {
    __shared__ f16 h0buf[2][16 * 128];   // ping-pong
    __shared__ f16 h1buf[2][16 * 128];
    __shared__ float sAgg[16 * Tt];
    const int tid = threadIdx.x;
    const int lane = tid & 63;
    const int uq = tid >> 6;          // wave 0..3
    const int l = lane & 15;
    const int quad = lane >> 4;
    const int n0 = blockIdx.x * 16;
    const int u0 = uq * 16 + l;       // pair-0 unit
    const int u1 = u0 + 64;           // pair-1 unit
    const int uch0 = u0 >> 3;         // LDS swizzle chunks
    const int uch1 = uch0 + 8;
    const int ulo = u0 & 7;           // same for u1 (u1 = u0+64)

    // dense prologue: load the block's 16 precomputed agg rows
    if (tid < 128) {
        int nl = tid >> 3, j = tid & 7;
        if (j < Tt)
            sAgg[nl * Tt + j] = agg[(size_t)(n0 + nl) * 8 + j];
    }

    float bI0[2] = {B0[u0], B0[u1]};
    float bF0[2] = {B0[128 + u0], B0[128 + u1]};
    float bG0[2] = {B0[256 + u0], B0[256 + u1]};
    float bO0[2] = {B0[384 + u0], B0[384 + u1]};
    float bI1[2] = {B1[u0], B1[u1]};
    float bF1[2] = {B1[128 + u0], B1[128 + u1]};
    float bG1[2] = {B1[256 + u0], B1[256 + u1]};
    float bO1[2] = {B1[384 + u0], B1[384 + u1]};

    f32x4 c0s[2], c1s[2];             // cell state per pair
    #pragma unroll
    for (int s = 0; s < 2; ++s) {
        c0s[s] = (f32x4){0.f, 0.f, 0.f, 0.f};
        c1s[s] = (f32x4){0.f, 0.f, 0.f, 0.f};
    }
    __syncthreads();   // sAgg visible

    f32x4 acc[2][4];                  // [pair][gate]
    #pragma unroll 1
    for (int t = 0; t < Tt; ++t) {
        const int cur = t & 1;
        const f16* h0r = h0buf[cur];
        const f16* h1r = h1buf[cur];
        f16* h0w = h0buf[cur ^ 1];
        f16* h1w = h1buf[cur ^ 1];

        // ======== layer 0: K = [feat(64) | h0(128)], NKT=6 ========
        #pragma unroll
        for (int s = 0; s < 2; ++s)
            #pragma unroll
            for (int g = 0; g < 4; ++g) acc[s][g] = (f32x4){0.f, 0.f, 0.f, 0.f};
        const float an = sAgg[l * Tt + t];

        // feat k-tiles (kt = 0,1): one A-frag shared by both pairs
        #pragma unroll
        for (int kt = 0; kt < 2; ++kt) {
            f16x8 af;
            #pragma unroll
            for (int j = 0; j < 8; ++j) {
                int k = kt * 32 + quad * 8 + j;
                af[j] = (f16)fmaxf(gw[k] * an + gb[k], 0.f);
            }
            const f16* bp = W0S + ((size_t)(uq * 6 + kt) * 4) * 1024 + lane * 8;
            #pragma unroll
            for (int g = 0; g < 4; ++g) {
                f16x8 b0 = *(const f16x8*)(bp + g * 1024);
                f16x8 b1 = *(const f16x8*)(bp + g * 1024 + 512);
                acc[0][g] = __builtin_amdgcn_mfma_f32_16x16x32_f16(af, b0, acc[0][g], 0, 0, 0);
                acc[1][g] = __builtin_amdgcn_mfma_f32_16x16x32_f16(af, b1, acc[1][g], 0, 0, 0);
            }
        }
        // h0 k-tiles (kt = 2..5): skip at t=0
        if (t > 0) {
            #pragma unroll 2
            for (int kt = 2; kt < 6; ++kt) {
                int ub = (kt - 2) * 4 + quad;
                f16x8 af = *(const f16x8*)&h0r[l * 128 + ((ub ^ l) << 3)];
                const f16* bp = W0S + ((size_t)(uq * 6 + kt) * 4) * 1024 + lane * 8;
                #pragma unroll
                for (int g = 0; g < 4; ++g) {
                    f16x8 b0 = *(const f16x8*)(bp + g * 1024);
                    f16x8 b1 = *(const f16x8*)(bp + g * 1024 + 512);
                    acc[0][g] = __builtin_amdgcn_mfma_f32_16x16x32_f16(af, b0, acc[0][g], 0, 0, 0);
                    acc[1][g] = __builtin_amdgcn_mfma_f32_16x16x32_f16(af, b1, acc[1][g], 0, 0, 0);
                }
            }
        }
        // L0 epilogue -> h0_new into the OTHER buffer
        #pragma unroll
        for (int s = 0; s < 2; ++s) {
            f32x4 cc = c0s[s];
            int uch = s ? uch1 : uch0;
            #pragma unroll
            for (int r = 0; r < 4; ++r) {
                float i_ = fsig(acc[s][0][r] + bI0[s]);
                float f_ = fsig(acc[s][1][r] + bF0[s]);
                float g_ = ftanh(acc[s][2][r] + bG0[s]);
                float o_ = fsig(acc[s][3][r] + bO0[s]);
                float cn = f_ * cc[r] + i_ * g_;
                cc[r] = cn;
                float hn = o_ * ftanh(cn);
                int node = quad * 4 + r;
                h0w[node * 128 + (((uch ^ node) << 3) | ulo)] = (f16)hn;
            }
            c0s[s] = cc;
        }
        __syncthreads();   // barrier 1 (4 waves)

        // ======== layer 1: K = [h0_new(128) | h1(128)], NKT=8 ========
        #pragma unroll
        for (int s = 0; s < 2; ++s)
            #pragma unroll
            for (int g = 0; g < 4; ++g) acc[s][g] = (f32x4){0.f, 0.f, 0.f, 0.f};
        {
            int ktmax = (t == 0) ? 4 : 8;
            #pragma unroll 2
            for (int kt = 0; kt < ktmax; ++kt) {
                const f16* hb = (kt < 4) ? h0w : h1r;
                int ub = (kt & 3) * 4 + quad;
                f16x8 af = *(const f16x8*)&hb[l * 128 + ((ub ^ l) << 3)];
                const f16* bp = W1S + ((size_t)(uq * 8 + kt) * 4) * 1024 + lane * 8;
                #pragma unroll
                for (int g = 0; g < 4; ++g) {
                    f16x8 b0 = *(const f16x8*)(bp + g * 1024);
                    f16x8 b1 = *(const f16x8*)(bp + g * 1024 + 512);
                    acc[0][g] = __builtin_amdgcn_mfma_f32_16x16x32_f16(af, b0, acc[0][g], 0, 0, 0);
                    acc[1][g] = __builtin_amdgcn_mfma_f32_16x16x32_f16(af, b1, acc[1][g], 0, 0, 0);
                }
            }
        }
        // L1 epilogue -> h1_new into the OTHER buffer
        #pragma unroll
        for (int s = 0; s < 2; ++s) {
            f32x4 cc = c1s[s];
            int uch = s ? uch1 : uch0;
            #pragma unroll
            for (int r = 0; r < 4; ++r) {
                float i_ = fsig(acc[s][0][r] + bI1[s]);
                float f_ = fsig(acc[s][1][r] + bF1[s]);
                float g_ = ftanh(acc[s][2][r] + bG1[s]);
                float o_ = fsig(acc[s][3][r] + bO1[s]);
                float cn = f_ * cc[r] + i_ * g_;
                cc[r] = cn;
                float hn = o_ * ftanh(cn);
                int node = quad * 4 + r;
                h1w[node * 128 + (((uch ^ node) << 3) | ulo)] = (f16)hn;
            }
            c1s[s] = cc;
        }
        __syncthreads();   // barrier 2 (4 waves)
    }

    // ======== head: wave 0 handles the block's 16 nodes ========
    const f16* h1f = h1buf[1];   // Tt=5 -> final h1 in buffer 1
    if (uq == 0) {
        f32x4 hacc[4];
        #pragma unroll
        for (int g = 0; g < 4; ++g) hacc[g] = (f32x4){0.f, 0.f, 0.f, 0.f};
        #pragma unroll
        for (int kt = 0; kt < 4; ++kt) {
            int ub = kt * 4 + quad;
            f16x8 a = *(const f16x8*)&h1f[l * 128 + ((ub ^ l) << 3)];
            #pragma unroll
            for (int g = 0; g < 4; ++g) {
                f16x8 b = *(const f16x8*)(pwS + (size_t)(g * 4 + kt) * 512 + lane * 8);
                hacc[g] = __builtin_amdgcn_mfma_f32_16x16x32_f16(a, b, hacc[g], 0, 0, 0);
            }
        }
        float yr[4] = {0.f, 0.f, 0.f, 0.f};
        #pragma unroll
        for (int g = 0; g < 4; ++g) {
            float pb = pb1[g * 16 + l];
            float pw = pw2[g * 16 + l];
            #pragma unroll
            for (int r = 0; r < 4; ++r)
                yr[r] += fmaxf(hacc[g][r] + pb, 0.f) * pw;
        }
        #pragma unroll
        for (int m = 1; m <= 8; m <<= 1) {
            #pragma unroll
            for (int r = 0; r < 4; ++r) yr[r] += __shfl_xor(yr[r], m);
        }
        if (l < 4) {
            float v = (l == 0) ? yr[0] : (l == 1) ? yr[1] : (l == 2) ? yr[2] : yr[3];
            int node = n0 + quad * 4 + l;
            out[node] = x[node * Tt + (Tt - 1)] + v + pb2[0];
        }
    }
}

extern "C" void kernel_launch(void* const* d_in, const int* in_sizes, int n_in,
                              void* d_out, int out_size, void* d_ws, size_t ws_size,
                              hipStream_t stream) {
    const float* x      = (const float*)d_in[0];
    const int*   ei     = (const int*)d_in[1];
    const float* gcn_w  = (const float*)d_in[2];
    const float* gcn_b  = (const float*)d_in[3];
    const float* w_ih0  = (const float*)d_in[4];
    const float* w_hh0  = (const float*)d_in[5];
    const float* b_ih0  = (const float*)d_in[6];
    const float* b_hh0  = (const float*)d_in[7];
    const float* w_ih1  = (const float*)d_in[8];
    const float* w_hh1  = (const float*)d_in[9];
    const float* b_ih1  = (const float*)d_in[10];
    const float* b_hh1  = (const float*)d_in[11];
    const float* pw1    = (const float*)d_in[12];
    const float* pb1    = (const float*)d_in[13];
    const float* pw2    = (const float*)d_in[14];
    const float* pb2    = (const float*)d_in[15];
    float* out = (float*)d_out;

    float* wsf  = (float*)d_ws;
    float* dinv = wsf + OFF_DINV;
    float* xs   = wsf + OFF_XS;
    float* agg  = wsf + OFF_AGG;
    int*   cnt  = (int*)(wsf + OFF_CNT);
    int*   slot = (int*)(wsf + OFF_SLOT);
    float* B0   = wsf + OFF_B0;
    float* B1   = wsf + OFF_B1;
    f16*   W0S  = (f16*)(wsf + OFF_W0S);
    f16*   W1S  = (f16*)(wsf + OFF_W1S);
    f16*   pwS  = (f16*)(wsf + OFF_PWS);

    // 0) zero the per-XCD count replicas (512 KB)
    hipMemsetAsync(cnt, 0, NREP * Nn * sizeof(int), stream);
    // 1) prep weights (pair-interleaved swizzle) + single-pass edge bucketize
    prep_fill<<<2092, 256, 0, stream>>>(w_ih0, w_hh0, b_ih0, b_hh0,
                                        w_ih1, w_hh1, b_ih1, b_hh1, pw1, ei,
                                        W0S, W1S, pwS, B0, B1, cnt, slot);
    // 2) dinv + prescale xs = x * dinv
    dinv_xs<<<(Nn + 255) / 256, 256, 0, stream>>>(cnt, x, dinv, xs);
    // 3) gather-aggregate at full-machine TLP
    gcn_agg<<<Nn / 32, 256, 0, stream>>>(cnt, slot, dinv, xs, agg);
    // 4) fused recurrence: 4-wave/16-node blocks, 4 blocks/CU
    recur_all<<<Nn / 16, 256, 0, stream>>>(agg, gcn_w, gcn_b, W0S, W1S, B0, B1,
                                           pwS, pb1, pw2, pb2, x, out);
}

// Round 9
// 191.917 us; speedup vs baseline: 2.1572x; 2.1572x over previous
//
#include <hip/hip_runtime.h>
#include <hip/hip_bf16.h>

// Problem constants (fixed by reference)
#define Nn 16000
#define Ee 256000
#define Tt 5
#define GATES 512  // 4*LH
#define NREP 8     // one replica per XCD (XCC_ID-indexed)
#define CAP 16     // slots per (node, XCD-replica); in-degree ~Poisson(2)

// Session ledger (measured):
//  R2: cooperative fusion = 397 µs fence/barrier stall. Never again.
//  R4: slot [r][n][16] = full-8MB fetch at 2.5/16 line util. Layout must be [i][r][n].
//  R6: inline per-source dinv loses to the dinv_xs precompute dispatch.
//  R7: "improved" folds (padded xs, parity split) are WORSE than R1's serial fold.
//  R8: launch_bounds tightening + doubled acc state -> VGPR 64 + 217 MB spill. Dead.
//  Cost model: ~8 µs per graph node; in-recur fold costs +5.6 µs < 8 µs node cost
//  -> 4-dispatch pipeline with R1's fold is the measured optimum (189.4 µs, R1).
// R9 = R1 restored verbatim (fold + champion t-loop), CAP 24->16 (halves prep_fill
// write-allocate; fold touches only planes i<c either way).

typedef _Float16 f16;
typedef __attribute__((ext_vector_type(8))) _Float16 f16x8;
typedef __attribute__((ext_vector_type(4))) float f32x4;

// ---- workspace layout (float units) ----
#define OFF_DINV 0
#define OFF_XS   (OFF_DINV + Nn)               // Nn*Tt fp32: xs[n][t] = x[n][t]*dinv[n]
#define OFF_CNT  (OFF_XS + Nn*Tt)              // NREP*Nn ints: per-XCD in-degree counts
#define OFF_SLOT (OFF_CNT + NREP*Nn)           // NREP*Nn*CAP ints, layout [i][r][n]
#define OFF_B0   (OFF_SLOT + NREP*Nn*CAP)      // 512
#define OFF_B1   (OFF_B0 + GATES)              // 512
#define OFF_W0S  (OFF_B1 + GATES)              // 512*192 f16 (swizzled)
#define OFF_W1S  (OFF_W0S + 512*192/2)         // 512*256 f16 (swizzled)
#define OFF_PWS  (OFF_W1S + 512*256/2)         // 64*128 f16 (swizzled head weights)
#define OFF_END  (OFF_PWS + 64*128/2)

__device__ __forceinline__ float fsig(float x) { return 1.f / (1.f + __expf(-x)); }
__device__ __forceinline__ float ftanh(float x) { return 1.f - 2.f / (1.f + __expf(2.f * x)); }

__device__ __forceinline__ unsigned xcc_id() {
    unsigned x;
    asm volatile("s_getreg_b32 %0, hwreg(HW_REG_XCC_ID)" : "=s"(x));
    return x & (NREP - 1);
}

// ---- prep + fill: swizzle weights, fold biases, AND bucketize edges ----
// Gate-contiguous B-frag swizzle: addr = ((g*NKT + kt)*4 + gate)*512 + (quad*16+l)*8 + j
// q = gate*128 + g*16 + l ; k = kt*32 + quad*8 + j.
// grid: [0,512) W0S | [512,1024) W1S | [1024,1028) biases | [1028,1092) pwS |
//       [1092,2092) edge fill: ONE atomic per edge; pos = fetch_add(cnt[r][d]) both
//       counts degree and allocates the slot. Slot layout [i][r][n]: dense in n.
__global__ void prep_fill(const float* __restrict__ w_ih0, const float* __restrict__ w_hh0,
                          const float* __restrict__ b_ih0, const float* __restrict__ b_hh0,
                          const float* __restrict__ w_ih1, const float* __restrict__ w_hh1,
                          const float* __restrict__ b_ih1, const float* __restrict__ b_hh1,
                          const float* __restrict__ pw1, const int* __restrict__ ei,
                          f16* __restrict__ W0S, f16* __restrict__ W1S, f16* __restrict__ pwS,
                          float* __restrict__ B0, float* __restrict__ B1,
                          int* __restrict__ cnt, int* __restrict__ slot) {
    int b = blockIdx.x, t = threadIdx.x;
    if (b >= 1092) {
        int e = (b - 1092) * 256 + t;          // 1000 blocks * 256 = Ee exactly
        int s = ei[e], d = ei[Ee + e];
        unsigned r = xcc_id();
        int pos = __hip_atomic_fetch_add(&cnt[r * Nn + d], 1,
                                         __ATOMIC_RELAXED, __HIP_MEMORY_SCOPE_WORKGROUP);
        if (pos < CAP)                          // overflow guard (P ~ 1e-6 across graph)
            slot[((size_t)pos * NREP + r) * Nn + d] = s;
        return;
    }
    if (b < 512) {
        if (t < 192) {
            int q = b, k = t;
            float v = (k < 64) ? w_ih0[q * 64 + k] : w_hh0[q * 128 + (k - 64)];
            int g = (q & 127) >> 4, l = q & 15, gate = q >> 7;
            int kt = k >> 5, quad = (k >> 3) & 3, j = k & 7;
            W0S[(((g * 6 + kt) * 4 + gate) * 64 + quad * 16 + l) * 8 + j] = (f16)v;
        }
    } else if (b < 1024) {
        int q = b - 512, k = t;
        float v = (k < 128) ? w_ih1[q * 128 + k] : w_hh1[q * 128 + (k - 128)];
        int g = (q & 127) >> 4, l = q & 15, gate = q >> 7;
        int kt = k >> 5, quad = (k >> 3) & 3, j = k & 7;
        W1S[(((g * 8 + kt) * 4 + gate) * 64 + quad * 16 + l) * 8 + j] = (f16)v;
    } else if (b < 1028) {
        int idx = (b - 1024) * 256 + t;
        if (idx < 512) B0[idx] = b_ih0[idx] + b_hh0[idx];
        else           B1[idx - 512] = b_ih1[idx - 512] + b_hh1[idx - 512];
    } else {
        if (t < 128) {
            int u = b - 1028, k = t;
            int g = u >> 4, lp = u & 15;
            int kt = k >> 5, quad = (k >> 3) & 3, j = k & 7;
            pwS[((g * 4 + kt) * 64 + quad * 16 + lp) * 8 + j] = (f16)pw1[u * 128 + k];
        }
    }
}

// ---- dinv + prescale: deg = 1 + sum of replica counts; xs = x * dinv ----
__global__ void dinv_xs(const int* __restrict__ cnt, const float* __restrict__ x,
                        float* __restrict__ dinv, float* __restrict__ xs) {
    int n = blockIdx.x * blockDim.x + threadIdx.x;
    if (n >= Nn) return;
    int deg = 1;  // self loop
    #pragma unroll
    for (int r = 0; r < NREP; ++r) deg += cnt[r * Nn + n];
    float dv = rsqrtf((float)deg);
    dinv[n] = dv;
    #pragma unroll
    for (int t = 0; t < Tt; ++t) xs[n * Tt + t] = x[n * Tt + t] * dv;
}

// ---- fused recurrence: CSR-lite gather fold (+dinv[d], +self-loop) + 5x2 LSTM + head ----
// Block = 512 thr = 8 waves, 32 nodes. Champion config:
// VGPR 128, unroll 2 on LDS kt loops, ping-pong h (2 barriers/step), no spill.
// Gate-contiguous W swizzle: 4 gate loads share one base (+0/1/2/3 KB imm).
// XOR-chunk h swizzle: 0 LDS bank conflicts (measured).
// Fold = R1's serial version (measured +5.6 µs vs dense-agg, cheaper than the
// ~8 µs an extra graph node costs): thread (node, replica), slots [i][r][n],
// 8-lane butterfly. t-loop onward byte-identical to the 94.5 µs champion.
__global__ __launch_bounds__(512, 2) void recur_all(
    const int* __restrict__ cnt, const int* __restrict__ slot,
    const float* __restrict__ dinv, const float* __restrict__ xs,
    const float* __restrict__ gw, const float* __restrict__ gb,
    const f16* __restrict__ W0S, const f16* __restrict__ W1S,
    const float* __restrict__ B0, const float* __restrict__ B1,
    const f16* __restrict__ pwS, const float* __restrict__ pb1,
    const float* __restrict__ pw2, const float* __restrict__ pb2,
    const float* __restrict__ x, float* __restrict__ out) {
    __shared__ f16 h0buf[2][32 * 128];   // ping-pong
    __shared__ f16 h1buf[2][32 * 128];
    __shared__ float sAgg[32 * Tt];      // folded agg for this block's 32 nodes
    const int tid = threadIdx.x;
    const int lane = tid & 63;
    const int uq = tid >> 6;          // wave = u16-group (0..7)
    const int l = lane & 15;
    const int quad = lane >> 4;
    const int n0 = blockIdx.x * 32;
    const int u = uq * 16 + l;        // this lane's hidden unit
    const int uch = u >> 3;           // u-chunk for LDS swizzle
    const int ulo = u & 7;

    // gather fold (R1 form): thread (node nl, replica r) sums its slots' prescaled
    // xs rows, then butterfly-reduce over the 8 replicas (lane-aligned groups of 8).
    if (tid < 256) {
        int nl = tid >> 3, r = tid & 7;
        int n = n0 + nl;
        int c = cnt[r * Nn + n];
        c = min(c, CAP);
        float s0 = 0.f, s1 = 0.f, s2 = 0.f, s3 = 0.f, s4 = 0.f;
        for (int i = 0; i < c; ++i) {
            int src = slot[((size_t)i * NREP + r) * Nn + n];
            const float* xr = xs + (size_t)src * Tt;
            s0 += xr[0]; s1 += xr[1]; s2 += xr[2]; s3 += xr[3]; s4 += xr[4];
        }
        #pragma unroll
        for (int m = 1; m < 8; m <<= 1) {
            s0 += __shfl_xor(s0, m);
            s1 += __shfl_xor(s1, m);
            s2 += __shfl_xor(s2, m);
            s3 += __shfl_xor(s3, m);
            s4 += __shfl_xor(s4, m);
        }
        if (r == 0) {
            float dv = dinv[n];
            const float* xr = x + (size_t)n * Tt;
            sAgg[nl * Tt + 0] = s0 * dv + xr[0] * dv * dv;
            sAgg[nl * Tt + 1] = s1 * dv + xr[1] * dv * dv;
            sAgg[nl * Tt + 2] = s2 * dv + xr[2] * dv * dv;
            sAgg[nl * Tt + 3] = s3 * dv + xr[3] * dv * dv;
            sAgg[nl * Tt + 4] = s4 * dv + xr[4] * dv * dv;
        }
    }

    const float bI0 = B0[u], bF0 = B0[128 + u], bG0 = B0[256 + u], bO0 = B0[384 + u];
    const float bI1 = B1[u], bF1 = B1[128 + u], bG1 = B1[256 + u], bO1 = B1[384 + u];

    f32x4 c0s[2], c1s[2];
    #pragma unroll
    for (int i = 0; i < 2; ++i) {
        c0s[i] = (f32x4){0.f, 0.f, 0.f, 0.f};
        c1s[i] = (f32x4){0.f, 0.f, 0.f, 0.f};
    }
    __syncthreads();   // sAgg visible

    f32x4 acc[2][4];
    #pragma unroll 1
    for (int t = 0; t < Tt; ++t) {
        const int cur = t & 1;        // read h[cur], write h[cur^1]
        const f16* h0r = h0buf[cur];
        const f16* h1r = h1buf[cur];
        f16* h0w = h0buf[cur ^ 1];
        f16* h1w = h1buf[cur ^ 1];

        // ======== layer 0: K = [feat(64) | h0(128)], NKT=6 ========
        #pragma unroll
        for (int i = 0; i < 2; ++i)
            #pragma unroll
            for (int g = 0; g < 4; ++g) acc[i][g] = (f32x4){0.f, 0.f, 0.f, 0.f};
        float an[2];
        #pragma unroll
        for (int i = 0; i < 2; ++i)
            an[i] = sAgg[(i * 16 + l) * Tt + t];

        // feat k-tiles (kt = 0,1): generated GCN features
        #pragma unroll
        for (int kt = 0; kt < 2; ++kt) {
            f16x8 af[2];
            #pragma unroll
            for (int j = 0; j < 8; ++j) {
                int k = kt * 32 + quad * 8 + j;
                float gwj = gw[k], gbj = gb[k];
                #pragma unroll
                for (int i = 0; i < 2; ++i)
                    af[i][j] = (f16)fmaxf(gwj * an[i] + gbj, 0.f);
            }
            const f16* bp = W0S + ((size_t)(uq * 6 + kt) * 4) * 512 + lane * 8;
            #pragma unroll
            for (int g = 0; g < 4; ++g) {
                f16x8 b = *(const f16x8*)(bp + g * 512);
                #pragma unroll
                for (int i = 0; i < 2; ++i)
                    acc[i][g] = __builtin_amdgcn_mfma_f32_16x16x32_f16(af[i], b, acc[i][g], 0, 0, 0);
            }
        }
        // h0 k-tiles (kt = 2..5): skip at t=0 (h0 zero). unroll 2: 2x loads in flight.
        if (t > 0) {
            #pragma unroll 2
            for (int kt = 2; kt < 6; ++kt) {
                int ub = (kt - 2) * 4 + quad;      // h0 u-chunk
                f16x8 af[2];
                #pragma unroll
                for (int i = 0; i < 2; ++i)
                    af[i] = *(const f16x8*)&h0r[(i * 16 + l) * 128 + ((ub ^ l) << 3)];
                const f16* bp = W0S + ((size_t)(uq * 6 + kt) * 4) * 512 + lane * 8;
                #pragma unroll
                for (int g = 0; g < 4; ++g) {
                    f16x8 b = *(const f16x8*)(bp + g * 512);
                    #pragma unroll
                    for (int i = 0; i < 2; ++i)
                        acc[i][g] = __builtin_amdgcn_mfma_f32_16x16x32_f16(af[i], b, acc[i][g], 0, 0, 0);
                }
            }
        }
        // L0 epilogue -> write h0_new into the OTHER buffer (no WAR with readers)
        #pragma unroll
        for (int i = 0; i < 2; ++i) {
            f32x4 cc = c0s[i];
            #pragma unroll
            for (int r = 0; r < 4; ++r) {
                float i_ = fsig(acc[i][0][r] + bI0);
                float f_ = fsig(acc[i][1][r] + bF0);
                float g_ = ftanh(acc[i][2][r] + bG0);
                float o_ = fsig(acc[i][3][r] + bO0);
                float cn = f_ * cc[r] + i_ * g_;
                cc[r] = cn;
                float hn = o_ * ftanh(cn);
                int node = i * 16 + quad * 4 + r;
                h0w[node * 128 + (((uch ^ (node & 15)) << 3) | ulo)] = (f16)hn;
            }
            c0s[i] = cc;
        }
        __syncthreads();   // barrier 1: h0_new visible to L1 readers

        // ======== layer 1: K = [h0_new(128) | h1(128)], NKT=8 ========
        #pragma unroll
        for (int i = 0; i < 2; ++i)
            #pragma unroll
            for (int g = 0; g < 4; ++g) acc[i][g] = (f32x4){0.f, 0.f, 0.f, 0.f};

        {
            int ktmax = (t == 0) ? 4 : 8;          // h1 zero at t=0
            #pragma unroll 2
            for (int kt = 0; kt < ktmax; ++kt) {
                const f16* hb = (kt < 4) ? h0w : h1r;   // h0_new | h1_old
                int ub = (kt & 3) * 4 + quad;
                f16x8 af[2];
                #pragma unroll
                for (int i = 0; i < 2; ++i)
                    af[i] = *(const f16x8*)&hb[(i * 16 + l) * 128 + ((ub ^ l) << 3)];
                const f16* bp = W1S + ((size_t)(uq * 8 + kt) * 4) * 512 + lane * 8;
                #pragma unroll
                for (int g = 0; g < 4; ++g) {
                    f16x8 b = *(const f16x8*)(bp + g * 512);
                    #pragma unroll
                    for (int i = 0; i < 2; ++i)
                        acc[i][g] = __builtin_amdgcn_mfma_f32_16x16x32_f16(af[i], b, acc[i][g], 0, 0, 0);
                }
            }
        }
        // L1 epilogue -> write h1_new into the OTHER buffer
        #pragma unroll
        for (int i = 0; i < 2; ++i) {
            f32x4 cc = c1s[i];
            #pragma unroll
            for (int r = 0; r < 4; ++r) {
                float i_ = fsig(acc[i][0][r] + bI1);
                float f_ = fsig(acc[i][1][r] + bF1);
                float g_ = ftanh(acc[i][2][r] + bG1);
                float o_ = fsig(acc[i][3][r] + bO1);
                float cn = f_ * cc[r] + i_ * g_;
                cc[r] = cn;
                float hn = o_ * ftanh(cn);
                int node = i * 16 + quad * 4 + r;
                h1w[node * 128 + (((uch ^ (node & 15)) << 3) | ulo)] = (f16)hn;
            }
            c1s[i] = cc;
        }
        __syncthreads();   // barrier 2: h1_new visible to next step's readers
    }

    // ======== head: out = x[:,4] + relu(h1@pw1.T+pb1)@pw2.T + pb2 ========
    // last step (t=4, cur=0) wrote h1buf[1]; waves 0..1 handle 16 nodes each
    const f16* h1f = h1buf[1];   // Tt=5 -> final h1 in buffer 1
    if (uq < 2) {
        f32x4 hacc[4];
        #pragma unroll
        for (int g = 0; g < 4; ++g) hacc[g] = (f32x4){0.f, 0.f, 0.f, 0.f};
        #pragma unroll
        for (int kt = 0; kt < 4; ++kt) {
            int ub = kt * 4 + quad;
            f16x8 a = *(const f16x8*)&h1f[(uq * 16 + l) * 128 + ((ub ^ l) << 3)];
            #pragma unroll
            for (int g = 0; g < 4; ++g) {
                f16x8 b = *(const f16x8*)(pwS + (size_t)(g * 4 + kt) * 512 + lane * 8);
                hacc[g] = __builtin_amdgcn_mfma_f32_16x16x32_f16(a, b, hacc[g], 0, 0, 0);
            }
        }
        float yr[4] = {0.f, 0.f, 0.f, 0.f};
        #pragma unroll
        for (int g = 0; g < 4; ++g) {
            float pb = pb1[g * 16 + l];
            float pw = pw2[g * 16 + l];
            #pragma unroll
            for (int r = 0; r < 4; ++r)
                yr[r] += fmaxf(hacc[g][r] + pb, 0.f) * pw;
        }
        #pragma unroll
        for (int m = 1; m <= 8; m <<= 1) {
            #pragma unroll
            for (int r = 0; r < 4; ++r) yr[r] += __shfl_xor(yr[r], m);
        }
        if (l < 4) {
            float v = (l == 0) ? yr[0] : (l == 1) ? yr[1] : (l == 2) ? yr[2] : yr[3];
            int node = n0 + uq * 16 + quad * 4 + l;
            out[node] = x[node * Tt + (Tt - 1)] + v + pb2[0];
        }
    }
}

extern "C" void kernel_launch(void* const* d_in, const int* in_sizes, int n_in,
                              void* d_out, int out_size, void* d_ws, size_t ws_size,
                              hipStream_t stream) {
    const float* x      = (const float*)d_in[0];
    const int*   ei     = (const int*)d_in[1];
    const float* gcn_w  = (const float*)d_in[2];
    const float* gcn_b  = (const float*)d_in[3];
    const float* w_ih0  = (const float*)d_in[4];
    const float* w_hh0  = (const float*)d_in[5];
    const float* b_ih0  = (const float*)d_in[6];
    const float* b_hh0  = (const float*)d_in[7];
    const float* w_ih1  = (const float*)d_in[8];
    const float* w_hh1  = (const float*)d_in[9];
    const float* b_ih1  = (const float*)d_in[10];
    const float* b_hh1  = (const float*)d_in[11];
    const float* pw1    = (const float*)d_in[12];
    const float* pb1    = (const float*)d_in[13];
    const float* pw2    = (const float*)d_in[14];
    const float* pb2    = (const float*)d_in[15];
    float* out = (float*)d_out;

    float* wsf  = (float*)d_ws;
    float* dinv = wsf + OFF_DINV;
    float* xs   = wsf + OFF_XS;
    int*   cnt  = (int*)(wsf + OFF_CNT);
    int*   slot = (int*)(wsf + OFF_SLOT);
    float* B0   = wsf + OFF_B0;
    float* B1   = wsf + OFF_B1;
    f16*   W0S  = (f16*)(wsf + OFF_W0S);
    f16*   W1S  = (f16*)(wsf + OFF_W1S);
    f16*   pwS  = (f16*)(wsf + OFF_PWS);

    // 0) zero the per-XCD count replicas only (512 KB)
    hipMemsetAsync(cnt, 0, NREP * Nn * sizeof(int), stream);
    // 1) prep weights + single-pass edge bucketize (counts + slots in ONE atomic/edge)
    prep_fill<<<2092, 256, 0, stream>>>(w_ih0, w_hh0, b_ih0, b_hh0,
                                        w_ih1, w_hh1, b_ih1, b_hh1, pw1, ei,
                                        W0S, W1S, pwS, B0, B1, cnt, slot);
    // 2) dinv + prescale xs = x * dinv
    dinv_xs<<<(Nn + 255) / 256, 256, 0, stream>>>(cnt, x, dinv, xs);
    // 3) fused recurrence (in-recur fold + dinv[d] + self-loop): LSTM + head
    recur_all<<<Nn / 32, 512, 0, stream>>>(cnt, slot, dinv, xs, gcn_w, gcn_b, W0S, W1S, B0, B1,
                                           pwS, pb1, pw2, pb2, x, out);
}

// Round 10
// 188.692 us; speedup vs baseline: 2.1941x; 1.0171x over previous
//
#include <hip/hip_runtime.h>
#include <hip/hip_bf16.h>

// Problem constants (fixed by reference)
#define Nn 16000
#define Ee 256000
#define Tt 5
#define GATES 512  // 4*LH
#define NREP 8     // one replica per XCD (XCC_ID-indexed)
#define CAP 16     // slots per (node, XCD-replica); in-degree ~Poisson(2)

// Session ledger (measured):
//  R2: cooperative fusion = 397 µs fence/barrier stall. Never again.
//  R4: slot [r][n][16] = full-8MB fetch at 2.5/16 line util. Layout must be [i][r][n].
//  R6: inline per-source dinv loses to the dinv_xs precompute dispatch.
//  R7: "improved" folds are WORSE than R1's serial fold.
//  R8: launch_bounds tightening + doubled acc state -> VGPR 64 + 217 MB spill. Dead.
//  R9: R1 config reproduced (recur 100.3, total 191.9; noise ±2.5 µs).
// R10: remove barrier 2 of each t-step (hazard analysis: one barrier/step suffices
// with the ping-pong buffers; head needs one final barrier). 11 -> 7 barriers;
// merged L1->next-L0 segment lets weight loads overlap epilogue VALU instead of
// being fenced by the pre-barrier vmcnt/lgkmcnt drain.

typedef _Float16 f16;
typedef __attribute__((ext_vector_type(8))) _Float16 f16x8;
typedef __attribute__((ext_vector_type(4))) float f32x4;

// ---- workspace layout (float units) ----
#define OFF_DINV 0
#define OFF_XS   (OFF_DINV + Nn)               // Nn*Tt fp32: xs[n][t] = x[n][t]*dinv[n]
#define OFF_CNT  (OFF_XS + Nn*Tt)              // NREP*Nn ints: per-XCD in-degree counts
#define OFF_SLOT (OFF_CNT + NREP*Nn)           // NREP*Nn*CAP ints, layout [i][r][n]
#define OFF_B0   (OFF_SLOT + NREP*Nn*CAP)      // 512
#define OFF_B1   (OFF_B0 + GATES)              // 512
#define OFF_W0S  (OFF_B1 + GATES)              // 512*192 f16 (swizzled)
#define OFF_W1S  (OFF_W0S + 512*192/2)         // 512*256 f16 (swizzled)
#define OFF_PWS  (OFF_W1S + 512*256/2)         // 64*128 f16 (swizzled head weights)
#define OFF_END  (OFF_PWS + 64*128/2)

__device__ __forceinline__ float fsig(float x) { return 1.f / (1.f + __expf(-x)); }
__device__ __forceinline__ float ftanh(float x) { return 1.f - 2.f / (1.f + __expf(2.f * x)); }

__device__ __forceinline__ unsigned xcc_id() {
    unsigned x;
    asm volatile("s_getreg_b32 %0, hwreg(HW_REG_XCC_ID)" : "=s"(x));
    return x & (NREP - 1);
}

// ---- prep + fill: swizzle weights, fold biases, AND bucketize edges ----
// Gate-contiguous B-frag swizzle: addr = ((g*NKT + kt)*4 + gate)*512 + (quad*16+l)*8 + j
// q = gate*128 + g*16 + l ; k = kt*32 + quad*8 + j.
// grid: [0,512) W0S | [512,1024) W1S | [1024,1028) biases | [1028,1092) pwS |
//       [1092,2092) edge fill: ONE atomic per edge; pos = fetch_add(cnt[r][d]) both
//       counts degree and allocates the slot. Slot layout [i][r][n]: dense in n.
__global__ void prep_fill(const float* __restrict__ w_ih0, const float* __restrict__ w_hh0,
                          const float* __restrict__ b_ih0, const float* __restrict__ b_hh0,
                          const float* __restrict__ w_ih1, const float* __restrict__ w_hh1,
                          const float* __restrict__ b_ih1, const float* __restrict__ b_hh1,
                          const float* __restrict__ pw1, const int* __restrict__ ei,
                          f16* __restrict__ W0S, f16* __restrict__ W1S, f16* __restrict__ pwS,
                          float* __restrict__ B0, float* __restrict__ B1,
                          int* __restrict__ cnt, int* __restrict__ slot) {
    int b = blockIdx.x, t = threadIdx.x;
    if (b >= 1092) {
        int e = (b - 1092) * 256 + t;          // 1000 blocks * 256 = Ee exactly
        int s = ei[e], d = ei[Ee + e];
        unsigned r = xcc_id();
        int pos = __hip_atomic_fetch_add(&cnt[r * Nn + d], 1,
                                         __ATOMIC_RELAXED, __HIP_MEMORY_SCOPE_WORKGROUP);
        if (pos < CAP)                          // overflow guard (P ~ 1e-6 across graph)
            slot[((size_t)pos * NREP + r) * Nn + d] = s;
        return;
    }
    if (b < 512) {
        if (t < 192) {
            int q = b, k = t;
            float v = (k < 64) ? w_ih0[q * 64 + k] : w_hh0[q * 128 + (k - 64)];
            int g = (q & 127) >> 4, l = q & 15, gate = q >> 7;
            int kt = k >> 5, quad = (k >> 3) & 3, j = k & 7;
            W0S[(((g * 6 + kt) * 4 + gate) * 64 + quad * 16 + l) * 8 + j] = (f16)v;
        }
    } else if (b < 1024) {
        int q = b - 512, k = t;
        float v = (k < 128) ? w_ih1[q * 128 + k] : w_hh1[q * 128 + (k - 128)];
        int g = (q & 127) >> 4, l = q & 15, gate = q >> 7;
        int kt = k >> 5, quad = (k >> 3) & 3, j = k & 7;
        W1S[(((g * 8 + kt) * 4 + gate) * 64 + quad * 16 + l) * 8 + j] = (f16)v;
    } else if (b < 1028) {
        int idx = (b - 1024) * 256 + t;
        if (idx < 512) B0[idx] = b_ih0[idx] + b_hh0[idx];
        else           B1[idx - 512] = b_ih1[idx - 512] + b_hh1[idx - 512];
    } else {
        if (t < 128) {
            int u = b - 1028, k = t;
            int g = u >> 4, lp = u & 15;
            int kt = k >> 5, quad = (k >> 3) & 3, j = k & 7;
            pwS[((g * 4 + kt) * 64 + quad * 16 + lp) * 8 + j] = (f16)pw1[u * 128 + k];
        }
    }
}

// ---- dinv + prescale: deg = 1 + sum of replica counts; xs = x * dinv ----
__global__ void dinv_xs(const int* __restrict__ cnt, const float* __restrict__ x,
                        float* __restrict__ dinv, float* __restrict__ xs) {
    int n = blockIdx.x * blockDim.x + threadIdx.x;
    if (n >= Nn) return;
    int deg = 1;  // self loop
    #pragma unroll
    for (int r = 0; r < NREP; ++r) deg += cnt[r * Nn + n];
    float dv = rsqrtf((float)deg);
    dinv[n] = dv;
    #pragma unroll
    for (int t = 0; t < Tt; ++t) xs[n * Tt + t] = x[n * Tt + t] * dv;
}

// ---- fused recurrence: CSR-lite gather fold + 5x2 LSTM + head ----
// Block = 512 thr = 8 waves, 32 nodes. Champion config:
// VGPR 128, unroll 2 on LDS kt loops, ping-pong h, no spill.
// Gate-contiguous W swizzle: 4 gate loads share one base (+0/1/2/3 KB imm).
// XOR-chunk h swizzle: 0 LDS bank conflicts (measured).
// R10: ONE barrier per t-step (was 2). Hazard proof:
//  - h0w writes (L0-epi, t) -> readers L1(t) & L0(t+1): both after barrier(t).
//  - h1w writes (L1-epi, t) -> reader L1(t+1): after barrier(t+1).
//  - WAR h0buf[cur(t)]: last read by L0(t) pre-barrier(t); rewritten L0-epi(t+1)
//    post-barrier(t). WAR h1buf[cur(t)]: last read L1(t) pre-barrier(t+1);
//    rewritten L1-epi(t+1) post-barrier(t+1).
//  - head reads full h1buf[1]: one final barrier after the loop.
__global__ __launch_bounds__(512, 2) void recur_all(
    const int* __restrict__ cnt, const int* __restrict__ slot,
    const float* __restrict__ dinv, const float* __restrict__ xs,
    const float* __restrict__ gw, const float* __restrict__ gb,
    const f16* __restrict__ W0S, const f16* __restrict__ W1S,
    const float* __restrict__ B0, const float* __restrict__ B1,
    const f16* __restrict__ pwS, const float* __restrict__ pb1,
    const float* __restrict__ pw2, const float* __restrict__ pb2,
    const float* __restrict__ x, float* __restrict__ out) {
    __shared__ f16 h0buf[2][32 * 128];   // ping-pong
    __shared__ f16 h1buf[2][32 * 128];
    __shared__ float sAgg[32 * Tt];      // folded agg for this block's 32 nodes
    const int tid = threadIdx.x;
    const int lane = tid & 63;
    const int uq = tid >> 6;          // wave = u16-group (0..7)
    const int l = lane & 15;
    const int quad = lane >> 4;
    const int n0 = blockIdx.x * 32;
    const int u = uq * 16 + l;        // this lane's hidden unit
    const int uch = u >> 3;           // u-chunk for LDS swizzle
    const int ulo = u & 7;

    // gather fold (R1 form): thread (node nl, replica r) sums its slots' prescaled
    // xs rows, then butterfly-reduce over the 8 replicas (lane-aligned groups of 8).
    if (tid < 256) {
        int nl = tid >> 3, r = tid & 7;
        int n = n0 + nl;
        int c = cnt[r * Nn + n];
        c = min(c, CAP);
        float s0 = 0.f, s1 = 0.f, s2 = 0.f, s3 = 0.f, s4 = 0.f;
        for (int i = 0; i < c; ++i) {
            int src = slot[((size_t)i * NREP + r) * Nn + n];
            const float* xr = xs + (size_t)src * Tt;
            s0 += xr[0]; s1 += xr[1]; s2 += xr[2]; s3 += xr[3]; s4 += xr[4];
        }
        #pragma unroll
        for (int m = 1; m < 8; m <<= 1) {
            s0 += __shfl_xor(s0, m);
            s1 += __shfl_xor(s1, m);
            s2 += __shfl_xor(s2, m);
            s3 += __shfl_xor(s3, m);
            s4 += __shfl_xor(s4, m);
        }
        if (r == 0) {
            float dv = dinv[n];
            const float* xr = x + (size_t)n * Tt;
            sAgg[nl * Tt + 0] = s0 * dv + xr[0] * dv * dv;
            sAgg[nl * Tt + 1] = s1 * dv + xr[1] * dv * dv;
            sAgg[nl * Tt + 2] = s2 * dv + xr[2] * dv * dv;
            sAgg[nl * Tt + 3] = s3 * dv + xr[3] * dv * dv;
            sAgg[nl * Tt + 4] = s4 * dv + xr[4] * dv * dv;
        }
    }

    const float bI0 = B0[u], bF0 = B0[128 + u], bG0 = B0[256 + u], bO0 = B0[384 + u];
    const float bI1 = B1[u], bF1 = B1[128 + u], bG1 = B1[256 + u], bO1 = B1[384 + u];

    f32x4 c0s[2], c1s[2];
    #pragma unroll
    for (int i = 0; i < 2; ++i) {
        c0s[i] = (f32x4){0.f, 0.f, 0.f, 0.f};
        c1s[i] = (f32x4){0.f, 0.f, 0.f, 0.f};
    }
    __syncthreads();   // sAgg visible

    f32x4 acc[2][4];
    #pragma unroll 1
    for (int t = 0; t < Tt; ++t) {
        const int cur = t & 1;        // read h[cur], write h[cur^1]
        const f16* h0r = h0buf[cur];
        const f16* h1r = h1buf[cur];
        f16* h0w = h0buf[cur ^ 1];
        f16* h1w = h1buf[cur ^ 1];

        // ======== layer 0: K = [feat(64) | h0(128)], NKT=6 ========
        #pragma unroll
        for (int i = 0; i < 2; ++i)
            #pragma unroll
            for (int g = 0; g < 4; ++g) acc[i][g] = (f32x4){0.f, 0.f, 0.f, 0.f};
        float an[2];
        #pragma unroll
        for (int i = 0; i < 2; ++i)
            an[i] = sAgg[(i * 16 + l) * Tt + t];

        // feat k-tiles (kt = 0,1): generated GCN features
        #pragma unroll
        for (int kt = 0; kt < 2; ++kt) {
            f16x8 af[2];
            #pragma unroll
            for (int j = 0; j < 8; ++j) {
                int k = kt * 32 + quad * 8 + j;
                float gwj = gw[k], gbj = gb[k];
                #pragma unroll
                for (int i = 0; i < 2; ++i)
                    af[i][j] = (f16)fmaxf(gwj * an[i] + gbj, 0.f);
            }
            const f16* bp = W0S + ((size_t)(uq * 6 + kt) * 4) * 512 + lane * 8;
            #pragma unroll
            for (int g = 0; g < 4; ++g) {
                f16x8 b = *(const f16x8*)(bp + g * 512);
                #pragma unroll
                for (int i = 0; i < 2; ++i)
                    acc[i][g] = __builtin_amdgcn_mfma_f32_16x16x32_f16(af[i], b, acc[i][g], 0, 0, 0);
            }
        }
        // h0 k-tiles (kt = 2..5): skip at t=0 (h0 zero). unroll 2: 2x loads in flight.
        if (t > 0) {
            #pragma unroll 2
            for (int kt = 2; kt < 6; ++kt) {
                int ub = (kt - 2) * 4 + quad;      // h0 u-chunk
                f16x8 af[2];
                #pragma unroll
                for (int i = 0; i < 2; ++i)
                    af[i] = *(const f16x8*)&h0r[(i * 16 + l) * 128 + ((ub ^ l) << 3)];
                const f16* bp = W0S + ((size_t)(uq * 6 + kt) * 4) * 512 + lane * 8;
                #pragma unroll
                for (int g = 0; g < 4; ++g) {
                    f16x8 b = *(const f16x8*)(bp + g * 512);
                    #pragma unroll
                    for (int i = 0; i < 2; ++i)
                        acc[i][g] = __builtin_amdgcn_mfma_f32_16x16x32_f16(af[i], b, acc[i][g], 0, 0, 0);
                }
            }
        }
        // L0 epilogue -> write h0_new into the OTHER buffer (no WAR with readers)
        #pragma unroll
        for (int i = 0; i < 2; ++i) {
            f32x4 cc = c0s[i];
            #pragma unroll
            for (int r = 0; r < 4; ++r) {
                float i_ = fsig(acc[i][0][r] + bI0);
                float f_ = fsig(acc[i][1][r] + bF0);
                float g_ = ftanh(acc[i][2][r] + bG0);
                float o_ = fsig(acc[i][3][r] + bO0);
                float cn = f_ * cc[r] + i_ * g_;
                cc[r] = cn;
                float hn = o_ * ftanh(cn);
                int node = i * 16 + quad * 4 + r;
                h0w[node * 128 + (((uch ^ (node & 15)) << 3) | ulo)] = (f16)hn;
            }
            c0s[i] = cc;
        }
        __syncthreads();   // the step's ONE barrier: h0_new visible to L1 readers;
                           // also orders prev-step h1w writes for this step's h1r reads

        // ======== layer 1: K = [h0_new(128) | h1(128)], NKT=8 ========
        #pragma unroll
        for (int i = 0; i < 2; ++i)
            #pragma unroll
            for (int g = 0; g < 4; ++g) acc[i][g] = (f32x4){0.f, 0.f, 0.f, 0.f};

        {
            int ktmax = (t == 0) ? 4 : 8;          // h1 zero at t=0
            #pragma unroll 2
            for (int kt = 0; kt < ktmax; ++kt) {
                const f16* hb = (kt < 4) ? h0w : h1r;   // h0_new | h1_old
                int ub = (kt & 3) * 4 + quad;
                f16x8 af[2];
                #pragma unroll
                for (int i = 0; i < 2; ++i)
                    af[i] = *(const f16x8*)&hb[(i * 16 + l) * 128 + ((ub ^ l) << 3)];
                const f16* bp = W1S + ((size_t)(uq * 8 + kt) * 4) * 512 + lane * 8;
                #pragma unroll
                for (int g = 0; g < 4; ++g) {
                    f16x8 b = *(const f16x8*)(bp + g * 512);
                    #pragma unroll
                    for (int i = 0; i < 2; ++i)
                        acc[i][g] = __builtin_amdgcn_mfma_f32_16x16x32_f16(af[i], b, acc[i][g], 0, 0, 0);
                }
            }
        }
        // L1 epilogue -> write h1_new into the OTHER buffer. NO barrier here (R10):
        // next step's L0 touches only h0 buffers + sAgg; h1w's readers sit behind
        // the NEXT step's barrier.
        #pragma unroll
        for (int i = 0; i < 2; ++i) {
            f32x4 cc = c1s[i];
            #pragma unroll
            for (int r = 0; r < 4; ++r) {
                float i_ = fsig(acc[i][0][r] + bI1);
                float f_ = fsig(acc[i][1][r] + bF1);
                float g_ = ftanh(acc[i][2][r] + bG1);
                float o_ = fsig(acc[i][3][r] + bO1);
                float cn = f_ * cc[r] + i_ * g_;
                cc[r] = cn;
                float hn = o_ * ftanh(cn);
                int node = i * 16 + quad * 4 + r;
                h1w[node * 128 + (((uch ^ (node & 15)) << 3) | ulo)] = (f16)hn;
            }
            c1s[i] = cc;
        }
    }
    __syncthreads();   // final barrier: all h1buf[1] writes visible to the head

    // ======== head: out = x[:,4] + relu(h1@pw1.T+pb1)@pw2.T + pb2 ========
    // last step (t=4, cur=0) wrote h1buf[1]; waves 0..1 handle 16 nodes each
    const f16* h1f = h1buf[1];   // Tt=5 -> final h1 in buffer 1
    if (uq < 2) {
        f32x4 hacc[4];
        #pragma unroll
        for (int g = 0; g < 4; ++g) hacc[g] = (f32x4){0.f, 0.f, 0.f, 0.f};
        #pragma unroll
        for (int kt = 0; kt < 4; ++kt) {
            int ub = kt * 4 + quad;
            f16x8 a = *(const f16x8*)&h1f[(uq * 16 + l) * 128 + ((ub ^ l) << 3)];
            #pragma unroll
            for (int g = 0; g < 4; ++g) {
                f16x8 b = *(const f16x8*)(pwS + (size_t)(g * 4 + kt) * 512 + lane * 8);
                hacc[g] = __builtin_amdgcn_mfma_f32_16x16x32_f16(a, b, hacc[g], 0, 0, 0);
            }
        }
        float yr[4] = {0.f, 0.f, 0.f, 0.f};
        #pragma unroll
        for (int g = 0; g < 4; ++g) {
            float pb = pb1[g * 16 + l];
            float pw = pw2[g * 16 + l];
            #pragma unroll
            for (int r = 0; r < 4; ++r)
                yr[r] += fmaxf(hacc[g][r] + pb, 0.f) * pw;
        }
        #pragma unroll
        for (int m = 1; m <= 8; m <<= 1) {
            #pragma unroll
            for (int r = 0; r < 4; ++r) yr[r] += __shfl_xor(yr[r], m);
        }
        if (l < 4) {
            float v = (l == 0) ? yr[0] : (l == 1) ? yr[1] : (l == 2) ? yr[2] : yr[3];
            int node = n0 + uq * 16 + quad * 4 + l;
            out[node] = x[node * Tt + (Tt - 1)] + v + pb2[0];
        }
    }
}

extern "C" void kernel_launch(void* const* d_in, const int* in_sizes, int n_in,
                              void* d_out, int out_size, void* d_ws, size_t ws_size,
                              hipStream_t stream) {
    const float* x      = (const float*)d_in[0];
    const int*   ei     = (const int*)d_in[1];
    const float* gcn_w  = (const float*)d_in[2];
    const float* gcn_b  = (const float*)d_in[3];
    const float* w_ih0  = (const float*)d_in[4];
    const float* w_hh0  = (const float*)d_in[5];
    const float* b_ih0  = (const float*)d_in[6];
    const float* b_hh0  = (const float*)d_in[7];
    const float* w_ih1  = (const float*)d_in[8];
    const float* w_hh1  = (const float*)d_in[9];
    const float* b_ih1  = (const float*)d_in[10];
    const float* b_hh1  = (const float*)d_in[11];
    const float* pw1    = (const float*)d_in[12];
    const float* pb1    = (const float*)d_in[13];
    const float* pw2    = (const float*)d_in[14];
    const float* pb2    = (const float*)d_in[15];
    float* out = (float*)d_out;

    float* wsf  = (float*)d_ws;
    float* dinv = wsf + OFF_DINV;
    float* xs   = wsf + OFF_XS;
    int*   cnt  = (int*)(wsf + OFF_CNT);
    int*   slot = (int*)(wsf + OFF_SLOT);
    float* B0   = wsf + OFF_B0;
    float* B1   = wsf + OFF_B1;
    f16*   W0S  = (f16*)(wsf + OFF_W0S);
    f16*   W1S  = (f16*)(wsf + OFF_W1S);
    f16*   pwS  = (f16*)(wsf + OFF_PWS);

    // 0) zero the per-XCD count replicas only (512 KB)
    hipMemsetAsync(cnt, 0, NREP * Nn * sizeof(int), stream);
    // 1) prep weights + single-pass edge bucketize (counts + slots in ONE atomic/edge)
    prep_fill<<<2092, 256, 0, stream>>>(w_ih0, w_hh0, b_ih0, b_hh0,
                                        w_ih1, w_hh1, b_ih1, b_hh1, pw1, ei,
                                        W0S, W1S, pwS, B0, B1, cnt, slot);
    // 2) dinv + prescale xs = x * dinv
    dinv_xs<<<(Nn + 255) / 256, 256, 0, stream>>>(cnt, x, dinv, xs);
    // 3) fused recurrence (in-recur fold + dinv[d] + self-loop): LSTM + head
    recur_all<<<Nn / 32, 512, 0, stream>>>(cnt, slot, dinv, xs, gcn_w, gcn_b, W0S, W1S, B0, B1,
                                           pwS, pb1, pw2, pb2, x, out);
}